// Round 14
// baseline (495.739 us; speedup 1.0000x reference)
//
#include <hip/hip_runtime.h>
#include <hip/hip_bf16.h>

#define IN_F 128
#define OUT_F 16
#define N_HEADS 4
#define OUT_C 64   // OUT_F * N_HEADS
#define ALPHA 0.2f
#define EPB 4096   // edges per partition block (npb = ceil(E/EPB) must be <= 256)
#define TILE 64    // dsts per bucket; bucket = dst >> 6
#define BUFCAP 2560  // LDS edge staging per bucket (mean 1279; +35 sigma)

typedef __attribute__((ext_vector_type(8))) short bf16x8;
typedef __attribute__((ext_vector_type(4))) float f32x4;

// ---- order-preserving float<->uint encoding for atomicMax on floats ----
__device__ __forceinline__ unsigned int enc_f(float f) {
  unsigned int u = __float_as_uint(f);
  return (u & 0x80000000u) ? ~u : (u | 0x80000000u);
}
__device__ __forceinline__ float dec_f(unsigned int u) {
  unsigned int b = (u & 0x80000000u) ? (u & 0x7FFFFFFFu) : ~u;
  return __uint_as_float(b);
}

__device__ __forceinline__ ushort f2bf(float f) {
  union { __hip_bfloat16 b; ushort u; } cv;
  cv.b = __float2bfloat16(f);
  return cv.u;
}
__device__ __forceinline__ float bf2f(ushort u) {
  return __uint_as_float(((unsigned int)u) << 16);
}

// ---- init scalars + zero btot + pack W (one tiny launch) ----
__global__ __launch_bounds__(256) void k_initpack(
    const float* __restrict__ W, uint4* __restrict__ Wp,
    unsigned int* gmax_s, unsigned int* gmax_d, float* gsum,
    int* btot, int nbkt)
{
  int t = threadIdx.x;
  if (t < N_HEADS) {
    gmax_s[t] = enc_f(-3.0e38f);
    gmax_d[t] = enc_f(-3.0e38f);
    gsum[t] = 0.f;
  }
  for (int i = t; i < nbkt; i += 256) btot[i] = 0;
  int lane = t & 63;
  int ks = t >> 6;
  int cl = lane & 15, kg = lane >> 4;
#pragma unroll
  for (int ct = 0; ct < 4; ++ct) {
    int c = ct * 16 + cl;
    int k0 = ks * 32 + kg * 8;
    union { ushort u[8]; uint4 q; } P;
#pragma unroll
    for (int j = 0; j < 8; ++j) P.u[j] = f2bf(W[(k0 + j) * OUT_C + c]);
    Wp[(ks * 4 + ct) * 64 + lane] = P.q;
  }
}

// ---- fused: blocks [0,npb) do edge partition; blocks [npb,npb+nmm) do MFMA
//      GEMM+scores. Independent work, one launch -> overlap. ----
__global__ __launch_bounds__(256) void k_mmpart(
    const float* __restrict__ h, const uint4* __restrict__ Wp,
    const float* __restrict__ a_src, const float* __restrict__ a_dst,
    ushort* __restrict__ Whb, float4* __restrict__ ssrc4, float4* __restrict__ sdst4,
    unsigned int* __restrict__ gmax_s, unsigned int* __restrict__ gmax_d,
    const int* __restrict__ ei, int2* __restrict__ pairs,
    int* __restrict__ boff, int* __restrict__ btot,
    int n_nodes, int n_edges, int nbkt, int npb)
{
  __shared__ int lh[1024];
  __shared__ int lw[1024];
  __shared__ int tsx[256];
  __shared__ int2 pbuf[EPB];      // 32 KB staging
  __shared__ float wmS[4][4], wmD[4][4];

  const int t = threadIdx.x;

  if (blockIdx.x < (unsigned)npb) {
    // ================= PART path =================
    const int base = blockIdx.x * EPB;
    const int n = min(EPB, n_edges - base);

    for (int i = t; i < 1024; i += 256) lh[i] = 0;
    __syncthreads();

    int4 sv[4], dv[4];
#pragma unroll
    for (int k = 0; k < 4; ++k) {
      int q4 = k * 256 + t;
      int e0 = q4 * 4;
      if (e0 + 3 < n) {
        sv[k] = ((const int4*)(ei + base))[q4];
        dv[k] = ((const int4*)(ei + n_edges + base))[q4];
      } else {
        int s0 = 0, s1 = 0, s2 = 0, s3 = 0, d0 = -1, d1 = -1, d2 = -1, d3 = -1;
        if (e0 + 0 < n) { s0 = ei[base + e0];     d0 = ei[n_edges + base + e0]; }
        if (e0 + 1 < n) { s1 = ei[base + e0 + 1]; d1 = ei[n_edges + base + e0 + 1]; }
        if (e0 + 2 < n) { s2 = ei[base + e0 + 2]; d2 = ei[n_edges + base + e0 + 2]; }
        if (e0 + 3 < n) { s3 = ei[base + e0 + 3]; d3 = ei[n_edges + base + e0 + 3]; }
        sv[k] = make_int4(s0, s1, s2, s3);
        dv[k] = make_int4(d0, d1, d2, d3);
      }
      int dd[4] = {dv[k].x, dv[k].y, dv[k].z, dv[k].w};
#pragma unroll
      for (int q = 0; q < 4; ++q)
        if (dd[q] >= 0) atomicAdd(&lh[dd[q] >> 6], 1);
    }
    __syncthreads();

    {
      int b0 = t * 4;
      int c0 = lh[b0], c1 = lh[b0 + 1], c2 = lh[b0 + 2], c3 = lh[b0 + 3];
      int my = c0 + c1 + c2 + c3;
      tsx[t] = my;
      __syncthreads();
#pragma unroll
      for (int off = 1; off < 256; off <<= 1) {
        int v = (t >= off) ? tsx[t - off] : 0;
        __syncthreads();
        tsx[t] += v;
        __syncthreads();
      }
      int ex = tsx[t] - my;
      lh[b0] = ex; ex += c0;
      lh[b0 + 1] = ex; ex += c1;
      lh[b0 + 2] = ex; ex += c2;
      lh[b0 + 3] = ex;
    }
    __syncthreads();
    for (int i = t; i < 1024; i += 256) lw[i] = lh[i];
    __syncthreads();

#pragma unroll
    for (int k = 0; k < 4; ++k) {
      int ss[4] = {sv[k].x, sv[k].y, sv[k].z, sv[k].w};
      int dd[4] = {dv[k].x, dv[k].y, dv[k].z, dv[k].w};
#pragma unroll
      for (int q = 0; q < 4; ++q) {
        if (dd[q] >= 0) {
          int pos = atomicAdd(&lw[dd[q] >> 6], 1);
          pbuf[pos] = make_int2(ss[q], dd[q]);
        }
      }
    }
    __syncthreads();

    for (int i = t; i < n; i += 256) pairs[(size_t)base + i] = pbuf[i];
    for (int i = t; i <= nbkt; i += 256)
      boff[(size_t)blockIdx.x * (nbkt + 1) + i] = (i < nbkt) ? lh[i] : n;
    for (int i = t; i < nbkt; i += 256) {
      int c = lw[i] - lh[i];
      if (c) atomicAdd(&btot[i], c);
    }
    return;
  }

  // ================= MM path =================
  const int bid = blockIdx.x - npb;
  const int wid = t >> 6, lane = t & 63;
  const int r0 = bid * 64 + wid * 16;
  const int arow = r0 + (lane & 15);
  const int rclamp = arow < n_nodes ? arow : n_nodes - 1;
  const float* hrow = h + (size_t)rclamp * IN_F + (lane >> 4) * 8;

  f32x4 acc[4];
#pragma unroll
  for (int ct = 0; ct < 4; ++ct) acc[ct] = (f32x4){0.f, 0.f, 0.f, 0.f};

#pragma unroll
  for (int ks = 0; ks < 4; ++ks) {
    float4 a0 = *(const float4*)(hrow + ks * 32);
    float4 a1 = *(const float4*)(hrow + ks * 32 + 4);
    union { ushort u[8]; bf16x8 v; } A;
    A.u[0] = f2bf(a0.x); A.u[1] = f2bf(a0.y); A.u[2] = f2bf(a0.z); A.u[3] = f2bf(a0.w);
    A.u[4] = f2bf(a1.x); A.u[5] = f2bf(a1.y); A.u[6] = f2bf(a1.z); A.u[7] = f2bf(a1.w);
#pragma unroll
    for (int ct = 0; ct < 4; ++ct) {
      union { uint4 q; bf16x8 v; } B;
      B.q = Wp[(ks * 4 + ct) * 64 + lane];
      acc[ct] = __builtin_amdgcn_mfma_f32_16x16x32_bf16(A.v, B.v, acc[ct], 0, 0, 0);
    }
  }

  const int cl = lane & 15, g = lane >> 4;
  float as_[4], ad_[4];
#pragma unroll
  for (int ct = 0; ct < 4; ++ct) { as_[ct] = a_src[ct * 16 + cl]; ad_[ct] = a_dst[ct * 16 + cl]; }

  float ms[4], md[4];
#pragma unroll
  for (int ct = 0; ct < 4; ++ct) { ms[ct] = -3.0e38f; md[ct] = -3.0e38f; }

#pragma unroll
  for (int j = 0; j < 4; ++j) {
    int r = r0 + g * 4 + j;
    bool rv = r < n_nodes;
    float ps[4], pd[4];
#pragma unroll
    for (int ct = 0; ct < 4; ++ct) {
      float v = acc[ct][j];
      if (rv) Whb[(size_t)r * OUT_C + ct * 16 + cl] = f2bf(v);
      ps[ct] = v * as_[ct];
      pd[ct] = v * ad_[ct];
    }
#pragma unroll
    for (int o = 1; o < 16; o <<= 1) {
#pragma unroll
      for (int ct = 0; ct < 4; ++ct) {
        ps[ct] += __shfl_xor(ps[ct], o);
        pd[ct] += __shfl_xor(pd[ct], o);
      }
    }
    if (rv && cl == 0) {
      ssrc4[r] = make_float4(ps[0], ps[1], ps[2], ps[3]);
      sdst4[r] = make_float4(pd[0], pd[1], pd[2], pd[3]);
    }
    if (rv) {
#pragma unroll
      for (int ct = 0; ct < 4; ++ct) {
        ms[ct] = fmaxf(ms[ct], ps[ct]);
        md[ct] = fmaxf(md[ct], pd[ct]);
      }
    }
  }
#pragma unroll
  for (int o = 16; o < 64; o <<= 1) {
#pragma unroll
    for (int ct = 0; ct < 4; ++ct) {
      ms[ct] = fmaxf(ms[ct], __shfl_xor(ms[ct], o));
      md[ct] = fmaxf(md[ct], __shfl_xor(md[ct], o));
    }
  }
  if (lane == 0) {
#pragma unroll
    for (int ct = 0; ct < 4; ++ct) { wmS[wid][ct] = ms[ct]; wmD[wid][ct] = md[ct]; }
  }
  __syncthreads();
  if (t < N_HEADS) {
    float vs = fmaxf(fmaxf(wmS[0][t], wmS[1][t]), fmaxf(wmS[2][t], wmS[3][t]));
    float vd = fmaxf(fmaxf(wmD[0][t], wmD[1][t]), fmaxf(wmD[2][t], wmD[3][t]));
    atomicMax(gmax_s + t, enc_f(vs));
    atomicMax(gmax_d + t, enc_f(vd));
  }
}

// ---- fused sort+aggregate: one block per bucket. Gather bucket edges into
//      LDS (unsorted), aggregate via LDS fp32 atomics into a 64x68 tile,
//      fold gsum, write UNNORMALIZED rows. No dst-sort, no sorted_src/offs. ----
__global__ __launch_bounds__(256) void k_aggsort(
    const int2* __restrict__ pairs, const int* __restrict__ boff,
    const float* __restrict__ ssrc, const float4* __restrict__ sdst4,
    const ushort* __restrict__ Whb, const unsigned int* __restrict__ gmax_s,
    const unsigned int* __restrict__ gmax_d, float* __restrict__ gsum,
    float* __restrict__ outraw, int npb, int nbkt, int n_nodes)
{
  const int b = blockIdx.x;
  const int dlo = b << 6;
  const int t = threadIdx.x;
  const int lane = t & 63, wv = t >> 6;
  __shared__ int ts[256];
  __shared__ int totsh;
  __shared__ int2 buf1[BUFCAP];      // 20 KB
  __shared__ float acc[TILE][68];    // 17 KB (pad 64->68: bank spread)
  __shared__ float sdl[TILE][N_HEADS];
  __shared__ float red[4][4];

  // per-run counts for this bucket + block scan -> staging bases
  int cnt = 0, bo = 0;
  if (t < npb) {
    const int* bp = boff + (size_t)t * (nbkt + 1) + b;
    bo = bp[0];
    cnt = bp[1] - bo;
  }
  ts[t] = cnt;
  __syncthreads();
#pragma unroll
  for (int off = 1; off < 256; off <<= 1) {
    int v = (t >= off) ? ts[t - off] : 0;
    __syncthreads();
    ts[t] += v;
    __syncthreads();
  }
  int base = ts[t] - cnt;
  if (t == 255) totsh = ts[255];

  // zero acc, load sdl
  for (int i = t; i < TILE * 68; i += 256) ((float*)acc)[i] = 0.f;
  if (t < TILE) {
    int d = dlo + t;
    float4 v = (d < n_nodes) ? sdst4[d] : make_float4(0.f, 0.f, 0.f, 0.f);
    sdl[t][0] = v.x; sdl[t][1] = v.y; sdl[t][2] = v.z; sdl[t][3] = v.w;
  }
  __syncthreads();
  const int total = min(totsh, BUFCAP);   // statistically never clamps

  // gather this bucket's runs into LDS staging (thread t owns run t)
  if (cnt > 0 && base < BUFCAP) {
    const int2* rp = pairs + (size_t)t * EPB + bo;
    int lim = min(cnt, BUFCAP - base);
    for (int j = 0; j < lim; ++j) buf1[base + j] = rp[j];
  }
  __syncthreads();

  // aggregate: quarter-wave per edge, 2-deep ILP; wave wv owns a chunk
  const int g = lane >> 4;            // quarter index
  const int c4 = lane & 15;           // channel group
  const int head = c4 >> 2;
  float m = dec_f(gmax_s[head]) + dec_f(gmax_d[head]);
  float M = m > 0.f ? m : ALPHA * m;

  const int chunk = (total + 3) >> 2;
  const int e0 = wv * chunk;
  const int e1 = min(total, e0 + chunk);
  float wacc = 0.f;
  for (int j = e0; j < e1; j += 8) {
    int je0 = j + g, je1 = j + 4 + g;
    bool v0 = je0 < e1, v1 = je1 < e1;
    int2 p0 = buf1[v0 ? je0 : e0];
    int2 p1 = buf1[v1 ? je1 : e0];
    int s0 = p0.x, s1 = p1.x;
    int dl0 = p0.y & 63, dl1 = p1.y & 63;
    float sc0 = ssrc[s0 * N_HEADS + head] + sdl[dl0][head];
    float sc1 = ssrc[s1 * N_HEADS + head] + sdl[dl1][head];
    sc0 = sc0 > 0.f ? sc0 : ALPHA * sc0;
    sc1 = sc1 > 0.f ? sc1 : ALPHA * sc1;
    float w0 = __expf(sc0 - M);
    float w1 = __expf(sc1 - M);
    w0 = v0 ? w0 : 0.f;
    w1 = v1 ? w1 : 0.f;
    ushort4 va = *(const ushort4*)(Whb + (size_t)s0 * OUT_C + c4 * 4);
    ushort4 vb = *(const ushort4*)(Whb + (size_t)s1 * OUT_C + c4 * 4);
    atomicAdd(&acc[dl0][c4 * 4 + 0], w0 * bf2f(va.x));
    atomicAdd(&acc[dl0][c4 * 4 + 1], w0 * bf2f(va.y));
    atomicAdd(&acc[dl0][c4 * 4 + 2], w0 * bf2f(va.z));
    atomicAdd(&acc[dl0][c4 * 4 + 3], w0 * bf2f(va.w));
    atomicAdd(&acc[dl1][c4 * 4 + 0], w1 * bf2f(vb.x));
    atomicAdd(&acc[dl1][c4 * 4 + 1], w1 * bf2f(vb.y));
    atomicAdd(&acc[dl1][c4 * 4 + 2], w1 * bf2f(vb.z));
    atomicAdd(&acc[dl1][c4 * 4 + 3], w1 * bf2f(vb.w));
    if ((c4 & 3) == 0) wacc += w0 + w1;
  }
  // gsum fold: lanes with (c4&3)==0 hold partials for head=c4>>2
  wacc += __shfl_xor(wacc, 16);
  wacc += __shfl_xor(wacc, 32);
  if ((lane & 3) == 0 && lane < 16) red[wv][lane >> 2] = wacc;
  __syncthreads();
  if (t < N_HEADS) {
    float v = red[0][t] + red[1][t] + red[2][t] + red[3][t];
    atomicAdd(gsum + t, v);
  }

  // write unnormalized rows (coalesced)
  for (int r = wv; r < TILE; r += 4) {
    int d = dlo + r;
    if (d < n_nodes) outraw[(size_t)d * OUT_C + lane] = acc[r][lane];
  }
}

// ---- normalize + ReLU: out = relu(out) / gsum[head] ----
__global__ __launch_bounds__(256) void k_norm(
    float4* __restrict__ out, const float* __restrict__ gsum, int n4)
{
  int i = blockIdx.x * 256 + threadIdx.x;
  if (i >= n4) return;
  int head = (i & 15) >> 2;
  float inv = 1.f / gsum[head];
  float4 v = out[i];
  v.x = fmaxf(v.x, 0.f) * inv;
  v.y = fmaxf(v.y, 0.f) * inv;
  v.z = fmaxf(v.z, 0.f) * inv;
  v.w = fmaxf(v.w, 0.f) * inv;
  out[i] = v;
}

extern "C" void kernel_launch(void* const* d_in, const int* in_sizes, int n_in,
                              void* d_out, int out_size, void* d_ws, size_t ws_size,
                              hipStream_t stream) {
  const int*   ei    = (const int*)d_in[0];
  const float* h     = (const float*)d_in[1];
  const float* W     = (const float*)d_in[2];
  const float* a_src = (const float*)d_in[3];
  const float* a_dst = (const float*)d_in[4];
  float* out = (float*)d_out;

  const int n_edges = in_sizes[0] / 2;
  const int n_nodes = in_sizes[1] / IN_F;
  const int npb     = (n_edges + EPB - 1) / EPB;      // must be <= 256 (245 here)
  const int nbkt    = (n_nodes + TILE - 1) / TILE;    // must be <= 1024 (782 here)
  const int nmm     = (n_nodes + 63) / 64;

  char* ws = (char*)d_ws;
  size_t off = 0;
  auto alloc = [&](size_t bytes) { void* p = ws + off; off = (off + bytes + 15) & ~(size_t)15; return p; };
  ushort* Whb         = (ushort*)alloc((size_t)n_nodes * OUT_C * 2);
  float* ssrc         = (float*)alloc((size_t)n_nodes * N_HEADS * 4);
  float* sdst         = (float*)alloc((size_t)n_nodes * N_HEADS * 4);
  unsigned int* gmax_s= (unsigned int*)alloc(N_HEADS * 4);
  unsigned int* gmax_d= (unsigned int*)alloc(N_HEADS * 4);
  float* gsum         = (float*)alloc(N_HEADS * 4);
  int* btot           = (int*)alloc((size_t)nbkt * 4);
  int2* pairs         = (int2*)alloc((size_t)npb * EPB * 8);
  int* boff           = (int*)alloc((size_t)npb * (nbkt + 1) * 4);
  uint4* Wp           = (uint4*)alloc(16 * 64 * 16);   // 16 KB packed W

  k_initpack<<<1, 256, 0, stream>>>(W, Wp, gmax_s, gmax_d, gsum, btot, nbkt);
  k_mmpart<<<npb + nmm, 256, 0, stream>>>(h, Wp, a_src, a_dst, Whb,
      (float4*)ssrc, (float4*)sdst, gmax_s, gmax_d,
      ei, pairs, boff, btot, n_nodes, n_edges, nbkt, npb);
  k_aggsort<<<nbkt, 256, 0, stream>>>(pairs, boff, ssrc, (const float4*)sdst,
      Whb, gmax_s, gmax_d, gsum, out, npb, nbkt, n_nodes);
  k_norm<<<(n_nodes * 16 + 255) / 256, 256, 0, stream>>>((float4*)out, gsum, n_nodes * 16);
}

// Round 15
// 98.419 us; speedup vs baseline: 5.0370x; 5.0370x over previous
//
#include <hip/hip_runtime.h>
#include <hip/hip_bf16.h>

#define IN_F 128
#define OUT_F 16
#define N_HEADS 4
#define OUT_C 64   // OUT_F * N_HEADS
#define ALPHA 0.2f
#define EPB 4096   // edges per partition block (npb = ceil(E/EPB) must be <= 256)
#define TILE 64    // dsts per bucket; bucket = dst >> 6

typedef __attribute__((ext_vector_type(8))) short bf16x8;
typedef __attribute__((ext_vector_type(4))) float f32x4;

// ---- order-preserving float<->uint encoding for atomicMax on floats ----
__device__ __forceinline__ unsigned int enc_f(float f) {
  unsigned int u = __float_as_uint(f);
  return (u & 0x80000000u) ? ~u : (u | 0x80000000u);
}
__device__ __forceinline__ float dec_f(unsigned int u) {
  unsigned int b = (u & 0x80000000u) ? (u & 0x7FFFFFFFu) : ~u;
  return __uint_as_float(b);
}

__device__ __forceinline__ ushort f2bf(float f) {
  union { __hip_bfloat16 b; ushort u; } cv;
  cv.b = __float2bfloat16(f);
  return cv.u;
}
__device__ __forceinline__ float bf2f(ushort u) {
  return __uint_as_float(((unsigned int)u) << 16);
}

// ---- init scalars + zero btot + pack W (one tiny launch) ----
__global__ __launch_bounds__(256) void k_initpack(
    const float* __restrict__ W, uint4* __restrict__ Wp,
    unsigned int* gmax_s, unsigned int* gmax_d, float* gsum,
    int* btot, int nbkt)
{
  int t = threadIdx.x;
  if (t < N_HEADS) {
    gmax_s[t] = enc_f(-3.0e38f);
    gmax_d[t] = enc_f(-3.0e38f);
    gsum[t] = 0.f;
  }
  for (int i = t; i < nbkt; i += 256) btot[i] = 0;
  // pack W into B-fragment lane layout (bf16): wave = k-step
  int lane = t & 63;
  int ks = t >> 6;
  int cl = lane & 15, kg = lane >> 4;
#pragma unroll
  for (int ct = 0; ct < 4; ++ct) {
    int c = ct * 16 + cl;
    int k0 = ks * 32 + kg * 8;
    union { ushort u[8]; uint4 q; } P;
#pragma unroll
    for (int j = 0; j < 8; ++j) P.u[j] = f2bf(W[(k0 + j) * OUT_C + c]);
    Wp[(ks * 4 + ct) * 64 + lane] = P.q;
  }
}

// ---- fused: blocks [0,npb) do edge partition; blocks [npb,npb+nmm) do MFMA
//      GEMM+scores. Independent work, one launch -> overlap. ----
__global__ __launch_bounds__(256) void k_mmpart(
    const float* __restrict__ h, const uint4* __restrict__ Wp,
    const float* __restrict__ a_src, const float* __restrict__ a_dst,
    ushort* __restrict__ Whb, float4* __restrict__ ssrc4, float4* __restrict__ sdst4,
    unsigned int* __restrict__ gmax_s, unsigned int* __restrict__ gmax_d,
    const int* __restrict__ ei, int2* __restrict__ pairs,
    int* __restrict__ boff, int* __restrict__ btot,
    int n_nodes, int n_edges, int nbkt, int npb)
{
  __shared__ int lh[1024];
  __shared__ int lw[1024];
  __shared__ int tsx[256];
  __shared__ int2 pbuf[EPB];      // 32 KB staging
  __shared__ float wmS[4][4], wmD[4][4];

  const int t = threadIdx.x;

  if (blockIdx.x < (unsigned)npb) {
    // ================= PART path =================
    const int base = blockIdx.x * EPB;
    const int n = min(EPB, n_edges - base);

    for (int i = t; i < 1024; i += 256) lh[i] = 0;
    __syncthreads();

    int4 sv[4], dv[4];
#pragma unroll
    for (int k = 0; k < 4; ++k) {
      int q4 = k * 256 + t;
      int e0 = q4 * 4;
      if (e0 + 3 < n) {
        sv[k] = ((const int4*)(ei + base))[q4];
        dv[k] = ((const int4*)(ei + n_edges + base))[q4];
      } else {
        int s0 = 0, s1 = 0, s2 = 0, s3 = 0, d0 = -1, d1 = -1, d2 = -1, d3 = -1;
        if (e0 + 0 < n) { s0 = ei[base + e0];     d0 = ei[n_edges + base + e0]; }
        if (e0 + 1 < n) { s1 = ei[base + e0 + 1]; d1 = ei[n_edges + base + e0 + 1]; }
        if (e0 + 2 < n) { s2 = ei[base + e0 + 2]; d2 = ei[n_edges + base + e0 + 2]; }
        if (e0 + 3 < n) { s3 = ei[base + e0 + 3]; d3 = ei[n_edges + base + e0 + 3]; }
        sv[k] = make_int4(s0, s1, s2, s3);
        dv[k] = make_int4(d0, d1, d2, d3);
      }
      int dd[4] = {dv[k].x, dv[k].y, dv[k].z, dv[k].w};
#pragma unroll
      for (int q = 0; q < 4; ++q)
        if (dd[q] >= 0) atomicAdd(&lh[dd[q] >> 6], 1);
    }
    __syncthreads();

    {
      int b0 = t * 4;
      int c0 = lh[b0], c1 = lh[b0 + 1], c2 = lh[b0 + 2], c3 = lh[b0 + 3];
      int my = c0 + c1 + c2 + c3;
      tsx[t] = my;
      __syncthreads();
#pragma unroll
      for (int off = 1; off < 256; off <<= 1) {
        int v = (t >= off) ? tsx[t - off] : 0;
        __syncthreads();
        tsx[t] += v;
        __syncthreads();
      }
      int ex = tsx[t] - my;
      lh[b0] = ex; ex += c0;
      lh[b0 + 1] = ex; ex += c1;
      lh[b0 + 2] = ex; ex += c2;
      lh[b0 + 3] = ex;
    }
    __syncthreads();
    for (int i = t; i < 1024; i += 256) lw[i] = lh[i];
    __syncthreads();

#pragma unroll
    for (int k = 0; k < 4; ++k) {
      int ss[4] = {sv[k].x, sv[k].y, sv[k].z, sv[k].w};
      int dd[4] = {dv[k].x, dv[k].y, dv[k].z, dv[k].w};
#pragma unroll
      for (int q = 0; q < 4; ++q) {
        if (dd[q] >= 0) {
          int pos = atomicAdd(&lw[dd[q] >> 6], 1);
          pbuf[pos] = make_int2(ss[q], dd[q]);
        }
      }
    }
    __syncthreads();

    for (int i = t; i < n; i += 256) pairs[(size_t)base + i] = pbuf[i];
    for (int i = t; i <= nbkt; i += 256)
      boff[(size_t)blockIdx.x * (nbkt + 1) + i] = (i < nbkt) ? lh[i] : n;
    for (int i = t; i < nbkt; i += 256) {
      int c = lw[i] - lh[i];
      if (c) atomicAdd(&btot[i], c);
    }
    return;
  }

  // ================= MM path =================
  const int bid = blockIdx.x - npb;
  const int wid = t >> 6, lane = t & 63;
  const int r0 = bid * 64 + wid * 16;
  const int arow = r0 + (lane & 15);
  const int rclamp = arow < n_nodes ? arow : n_nodes - 1;
  const float* hrow = h + (size_t)rclamp * IN_F + (lane >> 4) * 8;

  f32x4 acc[4];
#pragma unroll
  for (int ct = 0; ct < 4; ++ct) acc[ct] = (f32x4){0.f, 0.f, 0.f, 0.f};

#pragma unroll
  for (int ks = 0; ks < 4; ++ks) {
    float4 a0 = *(const float4*)(hrow + ks * 32);
    float4 a1 = *(const float4*)(hrow + ks * 32 + 4);
    union { ushort u[8]; bf16x8 v; } A;
    A.u[0] = f2bf(a0.x); A.u[1] = f2bf(a0.y); A.u[2] = f2bf(a0.z); A.u[3] = f2bf(a0.w);
    A.u[4] = f2bf(a1.x); A.u[5] = f2bf(a1.y); A.u[6] = f2bf(a1.z); A.u[7] = f2bf(a1.w);
#pragma unroll
    for (int ct = 0; ct < 4; ++ct) {
      union { uint4 q; bf16x8 v; } B;
      B.q = Wp[(ks * 4 + ct) * 64 + lane];
      acc[ct] = __builtin_amdgcn_mfma_f32_16x16x32_bf16(A.v, B.v, acc[ct], 0, 0, 0);
    }
  }

  const int cl = lane & 15, g = lane >> 4;
  float as_[4], ad_[4];
#pragma unroll
  for (int ct = 0; ct < 4; ++ct) { as_[ct] = a_src[ct * 16 + cl]; ad_[ct] = a_dst[ct * 16 + cl]; }

  float ms[4], md[4];
#pragma unroll
  for (int ct = 0; ct < 4; ++ct) { ms[ct] = -3.0e38f; md[ct] = -3.0e38f; }

#pragma unroll
  for (int j = 0; j < 4; ++j) {
    int r = r0 + g * 4 + j;
    bool rv = r < n_nodes;
    float ps[4], pd[4];
#pragma unroll
    for (int ct = 0; ct < 4; ++ct) {
      float v = acc[ct][j];
      if (rv) Whb[(size_t)r * OUT_C + ct * 16 + cl] = f2bf(v);
      ps[ct] = v * as_[ct];
      pd[ct] = v * ad_[ct];
    }
#pragma unroll
    for (int o = 1; o < 16; o <<= 1) {
#pragma unroll
      for (int ct = 0; ct < 4; ++ct) {
        ps[ct] += __shfl_xor(ps[ct], o);
        pd[ct] += __shfl_xor(pd[ct], o);
      }
    }
    if (rv && cl == 0) {
      ssrc4[r] = make_float4(ps[0], ps[1], ps[2], ps[3]);
      sdst4[r] = make_float4(pd[0], pd[1], pd[2], pd[3]);
    }
    if (rv) {
#pragma unroll
      for (int ct = 0; ct < 4; ++ct) {
        ms[ct] = fmaxf(ms[ct], ps[ct]);
        md[ct] = fmaxf(md[ct], pd[ct]);
      }
    }
  }
#pragma unroll
  for (int o = 16; o < 64; o <<= 1) {
#pragma unroll
    for (int ct = 0; ct < 4; ++ct) {
      ms[ct] = fmaxf(ms[ct], __shfl_xor(ms[ct], o));
      md[ct] = fmaxf(md[ct], __shfl_xor(md[ct], o));
    }
  }
  if (lane == 0) {
#pragma unroll
    for (int ct = 0; ct < 4; ++ct) { wmS[wid][ct] = ms[ct]; wmD[wid][ct] = md[ct]; }
  }
  __syncthreads();
  if (t < N_HEADS) {
    float vs = fmaxf(fmaxf(wmS[0][t], wmS[1][t]), fmaxf(wmS[2][t], wmS[3][t]));
    float vd = fmaxf(fmaxf(wmD[0][t], wmD[1][t]), fmaxf(wmD[2][t], wmD[3][t]));
    atomicMax(gmax_s + t, enc_f(vs));
    atomicMax(gmax_d + t, enc_f(vd));
  }
}

// ---- per-bucket LDS sort: inline gbase prefix, gather runs, sort by dst,
//      direct scatter to block-private global span fused with exp/gsum. ----
__global__ __launch_bounds__(256) void k_sortb(
    const int2* __restrict__ pairs, const int* __restrict__ boff,
    const int* __restrict__ btot, const float4* __restrict__ ssrc4,
    const float4* __restrict__ sdst4, const unsigned int* __restrict__ gmax_s,
    const unsigned int* __restrict__ gmax_d, float* __restrict__ gsum,
    int* __restrict__ sorted_src, int* __restrict__ offs,
    int npb, int nbkt, int n_edges, int n_nodes)
{
  const int b = blockIdx.x;
  const int t = threadIdx.x;
  const int lane = t & 63, wv = t >> 6;
  __shared__ int ts[256];
  __shared__ int hist[65];
  __shared__ int hcur[64];
  __shared__ int totsh, gbsh;
  __shared__ int gred[4];
  __shared__ float red[4][4];
  __shared__ int2 buf1[4096];   // 32 KB

  // inline gbase: gb = sum_{i<b} btot[i]
  {
    int partial = 0;
    for (int i = t; i < b; i += 256) partial += btot[i];
#pragma unroll
    for (int o = 32; o; o >>= 1) partial += __shfl_down(partial, o);
    if (lane == 0) gred[wv] = partial;
  }

  // per-run counts for this bucket + block scan -> staging bases
  int cnt = 0, bo = 0;
  if (t < npb) {
    const int* bp = boff + (size_t)t * (nbkt + 1) + b;
    bo = bp[0];
    cnt = bp[1] - bo;
  }
  ts[t] = cnt;
  __syncthreads();
  if (t == 0) gbsh = gred[0] + gred[1] + gred[2] + gred[3];
#pragma unroll
  for (int off = 1; off < 256; off <<= 1) {
    int v = (t >= off) ? ts[t - off] : 0;
    __syncthreads();
    ts[t] += v;
    __syncthreads();
  }
  int base = ts[t] - cnt;
  if (t == 255) totsh = ts[255];
  for (int i = t; i < 65; i += 256) hist[i] = 0;
  __syncthreads();
  const int total = min(totsh, 4096);   // statistically never clamps
  const int gb = gbsh;

  // gather this bucket's runs into LDS staging (thread t owns run t)
  if (cnt > 0 && base < 4096) {
    const int2* rp = pairs + (size_t)t * EPB + bo;
    int lim = min(cnt, 4096 - base);
    for (int j = 0; j < lim; ++j) buf1[base + j] = rp[j];
  }
  __syncthreads();

  // 64-bin histogram + prefix
  for (int i = t; i < total; i += 256) atomicAdd(&hist[buf1[i].y & 63], 1);
  __syncthreads();
  if (t == 0) {
    int run = 0;
#pragma unroll
    for (int i = 0; i < 64; ++i) { int c = hist[i]; hist[i] = run; run += c; }
    hist[64] = run;
  }
  __syncthreads();
  for (int i = t; i < 64; i += 256) hcur[i] = hist[i];
  __syncthreads();

  // scatter directly to global (block-private ~5KB span, L2-resident)
  // fused with weight exp + gsum accumulation
  float M0, M1, M2, M3;
  {
    float m0 = dec_f(gmax_s[0]) + dec_f(gmax_d[0]);
    float m1 = dec_f(gmax_s[1]) + dec_f(gmax_d[1]);
    float m2 = dec_f(gmax_s[2]) + dec_f(gmax_d[2]);
    float m3 = dec_f(gmax_s[3]) + dec_f(gmax_d[3]);
    M0 = m0 > 0.f ? m0 : ALPHA * m0;
    M1 = m1 > 0.f ? m1 : ALPHA * m1;
    M2 = m2 > 0.f ? m2 : ALPHA * m2;
    M3 = m3 > 0.f ? m3 : ALPHA * m3;
  }
  float ac0 = 0.f, ac1 = 0.f, ac2 = 0.f, ac3 = 0.f;
  for (int i = t; i < total; i += 256) {
    int2 p = buf1[i];
    int pos = atomicAdd(&hcur[p.y & 63], 1);
    sorted_src[gb + pos] = p.x;
    float4 a = ssrc4[p.x];
    float4 bb = sdst4[p.y];
    float e0 = a.x + bb.x; e0 = e0 > 0.f ? e0 : ALPHA * e0;
    float e1 = a.y + bb.y; e1 = e1 > 0.f ? e1 : ALPHA * e1;
    float e2 = a.z + bb.z; e2 = e2 > 0.f ? e2 : ALPHA * e2;
    float e3 = a.w + bb.w; e3 = e3 > 0.f ? e3 : ALPHA * e3;
    ac0 += __expf(e0 - M0); ac1 += __expf(e1 - M1);
    ac2 += __expf(e2 - M2); ac3 += __expf(e3 - M3);
  }

  // per-dst offsets straight from bin prefix
  if (t <= 64) {
    int d = b * TILE + t;
    if (d <= n_nodes) offs[d] = gb + hist[t];
  }

  // block reduce gsum partials -> 4 atomics
#pragma unroll
  for (int o = 32; o; o >>= 1) {
    ac0 += __shfl_down(ac0, o); ac1 += __shfl_down(ac1, o);
    ac2 += __shfl_down(ac2, o); ac3 += __shfl_down(ac3, o);
  }
  if (lane == 0) { red[wv][0] = ac0; red[wv][1] = ac1; red[wv][2] = ac2; red[wv][3] = ac3; }
  __syncthreads();
  if (t < 4) {
    float v = red[0][t] + red[1][t] + red[2][t] + red[3][t];
    atomicAdd(gsum + t, v);
  }
}

// ---- aggregate: wave per dst, quarter-wave per edge, 8 edges/iter ILP ----
__global__ __launch_bounds__(256) void k_agg(
    const int* __restrict__ offs, const int* __restrict__ sorted_src,
    const float* __restrict__ ssrc, const float4* __restrict__ sdst4,
    const ushort* __restrict__ Whb, const unsigned int* __restrict__ gmax_s,
    const unsigned int* __restrict__ gmax_d, const float* __restrict__ gsum,
    float* __restrict__ out, int n_nodes)
{
  int d = blockIdx.x * 4 + (threadIdx.x >> 6);
  if (d >= n_nodes) return;
  const int lane = threadIdx.x & 63;
  const int g = lane >> 4;            // quarter index
  const int c4 = lane & 15;           // channel group
  const int head = c4 >> 2;
  float m = dec_f(gmax_s[head]) + dec_f(gmax_d[head]);
  float M = m > 0.f ? m : ALPHA * m;
  float inv = 1.f / gsum[head];
  float4 sd4 = sdst4[d];
  float sdh = head == 0 ? sd4.x : head == 1 ? sd4.y : head == 2 ? sd4.z : sd4.w;

  int beg = offs[d], end = offs[d + 1];
  float a0 = 0.f, a1 = 0.f, a2 = 0.f, a3 = 0.f;
  for (int j = beg; j < end; j += 8) {
    int je0 = j + g, je1 = j + 4 + g;
    bool v0 = je0 < end, v1 = je1 < end;
    int s0 = sorted_src[v0 ? je0 : beg];
    int s1 = sorted_src[v1 ? je1 : beg];
    float sc0 = ssrc[s0 * N_HEADS + head] + sdh;
    float sc1 = ssrc[s1 * N_HEADS + head] + sdh;
    sc0 = sc0 > 0.f ? sc0 : ALPHA * sc0;
    sc1 = sc1 > 0.f ? sc1 : ALPHA * sc1;
    float w0 = __expf(sc0 - M);
    float w1 = __expf(sc1 - M);
    w0 = v0 ? w0 : 0.f;
    w1 = v1 ? w1 : 0.f;
    ushort4 va = *(const ushort4*)(Whb + (size_t)s0 * OUT_C + c4 * 4);
    ushort4 vb = *(const ushort4*)(Whb + (size_t)s1 * OUT_C + c4 * 4);
    a0 += w0 * bf2f(va.x) + w1 * bf2f(vb.x);
    a1 += w0 * bf2f(va.y) + w1 * bf2f(vb.y);
    a2 += w0 * bf2f(va.z) + w1 * bf2f(vb.z);
    a3 += w0 * bf2f(va.w) + w1 * bf2f(vb.w);
  }
  // sum across the 4 quarters (lanes differing in bits 4,5)
  a0 += __shfl_xor(a0, 16); a1 += __shfl_xor(a1, 16);
  a2 += __shfl_xor(a2, 16); a3 += __shfl_xor(a3, 16);
  a0 += __shfl_xor(a0, 32); a1 += __shfl_xor(a1, 32);
  a2 += __shfl_xor(a2, 32); a3 += __shfl_xor(a3, 32);
  if (g == 0) {
    float4 o;
    o.x = fmaxf(a0 * inv, 0.f);
    o.y = fmaxf(a1 * inv, 0.f);
    o.z = fmaxf(a2 * inv, 0.f);
    o.w = fmaxf(a3 * inv, 0.f);
    ((float4*)(out + (size_t)d * OUT_C))[c4] = o;
  }
}

extern "C" void kernel_launch(void* const* d_in, const int* in_sizes, int n_in,
                              void* d_out, int out_size, void* d_ws, size_t ws_size,
                              hipStream_t stream) {
  const int*   ei    = (const int*)d_in[0];
  const float* h     = (const float*)d_in[1];
  const float* W     = (const float*)d_in[2];
  const float* a_src = (const float*)d_in[3];
  const float* a_dst = (const float*)d_in[4];
  float* out = (float*)d_out;

  const int n_edges = in_sizes[0] / 2;
  const int n_nodes = in_sizes[1] / IN_F;
  const int npb     = (n_edges + EPB - 1) / EPB;      // must be <= 256 (245 here)
  const int nbkt    = (n_nodes + TILE - 1) / TILE;    // must be <= 1024 (782 here)
  const int nmm     = (n_nodes + 63) / 64;

  char* ws = (char*)d_ws;
  size_t off = 0;
  auto alloc = [&](size_t bytes) { void* p = ws + off; off = (off + bytes + 15) & ~(size_t)15; return p; };
  ushort* Whb         = (ushort*)alloc((size_t)n_nodes * OUT_C * 2);
  float* ssrc         = (float*)alloc((size_t)n_nodes * N_HEADS * 4);
  float* sdst         = (float*)alloc((size_t)n_nodes * N_HEADS * 4);
  unsigned int* gmax_s= (unsigned int*)alloc(N_HEADS * 4);
  unsigned int* gmax_d= (unsigned int*)alloc(N_HEADS * 4);
  float* gsum         = (float*)alloc(N_HEADS * 4);
  int* btot           = (int*)alloc((size_t)nbkt * 4);
  int* offs           = (int*)alloc(((size_t)n_nodes + 1) * 4);
  int* sorted_src     = (int*)alloc((size_t)n_edges * 4);
  int2* pairs         = (int2*)alloc((size_t)npb * EPB * 8);
  int* boff           = (int*)alloc((size_t)npb * (nbkt + 1) * 4);
  uint4* Wp           = (uint4*)alloc(16 * 64 * 16);   // 16 KB packed W

  k_initpack<<<1, 256, 0, stream>>>(W, Wp, gmax_s, gmax_d, gsum, btot, nbkt);
  k_mmpart<<<npb + nmm, 256, 0, stream>>>(h, Wp, a_src, a_dst, Whb,
      (float4*)ssrc, (float4*)sdst, gmax_s, gmax_d,
      ei, pairs, boff, btot, n_nodes, n_edges, nbkt, npb);
  k_sortb<<<nbkt, 256, 0, stream>>>(pairs, boff, btot, (const float4*)ssrc,
      (const float4*)sdst, gmax_s, gmax_d, gsum, sorted_src, offs,
      npb, nbkt, n_edges, n_nodes);
  k_agg<<<(n_nodes + 3) / 4, 256, 0, stream>>>(offs, sorted_src, ssrc,
      (const float4*)sdst, Whb, gmax_s, gmax_d, gsum, out, n_nodes);
}

// Round 16
// 97.436 us; speedup vs baseline: 5.0878x; 1.0101x over previous
//
#include <hip/hip_runtime.h>
#include <hip/hip_bf16.h>

#define IN_F 128
#define OUT_F 16
#define N_HEADS 4
#define OUT_C 64   // OUT_F * N_HEADS
#define ALPHA 0.2f
#define EPB 4096   // edges per partition block (npb = ceil(E/EPB) must be <= 256)
#define TILE 64    // dsts per bucket; bucket = dst >> 6

typedef __attribute__((ext_vector_type(8))) short bf16x8;
typedef __attribute__((ext_vector_type(4))) float f32x4;

// ---- order-preserving float<->uint encoding for atomicMax on floats ----
__device__ __forceinline__ unsigned int enc_f(float f) {
  unsigned int u = __float_as_uint(f);
  return (u & 0x80000000u) ? ~u : (u | 0x80000000u);
}
__device__ __forceinline__ float dec_f(unsigned int u) {
  unsigned int b = (u & 0x80000000u) ? (u & 0x7FFFFFFFu) : ~u;
  return __uint_as_float(b);
}

__device__ __forceinline__ ushort f2bf(float f) {
  union { __hip_bfloat16 b; ushort u; } cv;
  cv.b = __float2bfloat16(f);
  return cv.u;
}
__device__ __forceinline__ float bf2f(ushort u) {
  return __uint_as_float(((unsigned int)u) << 16);
}

// ---- init scalars + zero btot + pack W (one tiny launch) ----
__global__ __launch_bounds__(256) void k_initpack(
    const float* __restrict__ W, uint4* __restrict__ Wp,
    unsigned int* gmax_s, unsigned int* gmax_d, float* gsum,
    int* btot, int nbkt)
{
  int t = threadIdx.x;
  if (t < N_HEADS) {
    gmax_s[t] = enc_f(-3.0e38f);
    gmax_d[t] = enc_f(-3.0e38f);
    gsum[t] = 0.f;
  }
  for (int i = t; i < nbkt; i += 256) btot[i] = 0;
  // pack W into B-fragment lane layout (bf16): wave = k-step
  int lane = t & 63;
  int ks = t >> 6;
  int cl = lane & 15, kg = lane >> 4;
#pragma unroll
  for (int ct = 0; ct < 4; ++ct) {
    int c = ct * 16 + cl;
    int k0 = ks * 32 + kg * 8;
    union { ushort u[8]; uint4 q; } P;
#pragma unroll
    for (int j = 0; j < 8; ++j) P.u[j] = f2bf(W[(k0 + j) * OUT_C + c]);
    Wp[(ks * 4 + ct) * 64 + lane] = P.q;
  }
}

// ---- fused: blocks [0,npb) do edge partition; blocks [npb,npb+nmm) do MFMA
//      GEMM+scores. Independent work, one launch -> overlap. ----
__global__ __launch_bounds__(256) void k_mmpart(
    const float* __restrict__ h, const uint4* __restrict__ Wp,
    const float* __restrict__ a_src, const float* __restrict__ a_dst,
    ushort* __restrict__ Whb, float4* __restrict__ ssrc4, float4* __restrict__ sdst4,
    unsigned int* __restrict__ gmax_s, unsigned int* __restrict__ gmax_d,
    const int* __restrict__ ei, int2* __restrict__ pairs,
    int* __restrict__ boff, int* __restrict__ btot,
    int n_nodes, int n_edges, int nbkt, int npb)
{
  __shared__ int lh[1024];
  __shared__ int lw[1024];
  __shared__ int tsx[256];
  __shared__ int2 pbuf[EPB];      // 32 KB staging
  __shared__ float wmS[4][4], wmD[4][4];

  const int t = threadIdx.x;

  if (blockIdx.x < (unsigned)npb) {
    // ================= PART path =================
    const int base = blockIdx.x * EPB;
    const int n = min(EPB, n_edges - base);

    for (int i = t; i < 1024; i += 256) lh[i] = 0;
    __syncthreads();

    int4 sv[4], dv[4];
#pragma unroll
    for (int k = 0; k < 4; ++k) {
      int q4 = k * 256 + t;
      int e0 = q4 * 4;
      if (e0 + 3 < n) {
        sv[k] = ((const int4*)(ei + base))[q4];
        dv[k] = ((const int4*)(ei + n_edges + base))[q4];
      } else {
        int s0 = 0, s1 = 0, s2 = 0, s3 = 0, d0 = -1, d1 = -1, d2 = -1, d3 = -1;
        if (e0 + 0 < n) { s0 = ei[base + e0];     d0 = ei[n_edges + base + e0]; }
        if (e0 + 1 < n) { s1 = ei[base + e0 + 1]; d1 = ei[n_edges + base + e0 + 1]; }
        if (e0 + 2 < n) { s2 = ei[base + e0 + 2]; d2 = ei[n_edges + base + e0 + 2]; }
        if (e0 + 3 < n) { s3 = ei[base + e0 + 3]; d3 = ei[n_edges + base + e0 + 3]; }
        sv[k] = make_int4(s0, s1, s2, s3);
        dv[k] = make_int4(d0, d1, d2, d3);
      }
      int dd[4] = {dv[k].x, dv[k].y, dv[k].z, dv[k].w};
#pragma unroll
      for (int q = 0; q < 4; ++q)
        if (dd[q] >= 0) atomicAdd(&lh[dd[q] >> 6], 1);
    }
    __syncthreads();

    {
      int b0 = t * 4;
      int c0 = lh[b0], c1 = lh[b0 + 1], c2 = lh[b0 + 2], c3 = lh[b0 + 3];
      int my = c0 + c1 + c2 + c3;
      tsx[t] = my;
      __syncthreads();
#pragma unroll
      for (int off = 1; off < 256; off <<= 1) {
        int v = (t >= off) ? tsx[t - off] : 0;
        __syncthreads();
        tsx[t] += v;
        __syncthreads();
      }
      int ex = tsx[t] - my;
      lh[b0] = ex; ex += c0;
      lh[b0 + 1] = ex; ex += c1;
      lh[b0 + 2] = ex; ex += c2;
      lh[b0 + 3] = ex;
    }
    __syncthreads();
    for (int i = t; i < 1024; i += 256) lw[i] = lh[i];
    __syncthreads();

#pragma unroll
    for (int k = 0; k < 4; ++k) {
      int ss[4] = {sv[k].x, sv[k].y, sv[k].z, sv[k].w};
      int dd[4] = {dv[k].x, dv[k].y, dv[k].z, dv[k].w};
#pragma unroll
      for (int q = 0; q < 4; ++q) {
        if (dd[q] >= 0) {
          int pos = atomicAdd(&lw[dd[q] >> 6], 1);
          pbuf[pos] = make_int2(ss[q], dd[q]);
        }
      }
    }
    __syncthreads();

    for (int i = t; i < n; i += 256) pairs[(size_t)base + i] = pbuf[i];
    for (int i = t; i <= nbkt; i += 256)
      boff[(size_t)blockIdx.x * (nbkt + 1) + i] = (i < nbkt) ? lh[i] : n;
    for (int i = t; i < nbkt; i += 256) {
      int c = lw[i] - lh[i];
      if (c) atomicAdd(&btot[i], c);
    }
    return;
  }

  // ================= MM path =================
  const int bid = blockIdx.x - npb;
  const int wid = t >> 6, lane = t & 63;
  const int r0 = bid * 64 + wid * 16;
  const int arow = r0 + (lane & 15);
  const int rclamp = arow < n_nodes ? arow : n_nodes - 1;
  const float* hrow = h + (size_t)rclamp * IN_F + (lane >> 4) * 8;

  f32x4 acc[4];
#pragma unroll
  for (int ct = 0; ct < 4; ++ct) acc[ct] = (f32x4){0.f, 0.f, 0.f, 0.f};

#pragma unroll
  for (int ks = 0; ks < 4; ++ks) {
    float4 a0 = *(const float4*)(hrow + ks * 32);
    float4 a1 = *(const float4*)(hrow + ks * 32 + 4);
    union { ushort u[8]; bf16x8 v; } A;
    A.u[0] = f2bf(a0.x); A.u[1] = f2bf(a0.y); A.u[2] = f2bf(a0.z); A.u[3] = f2bf(a0.w);
    A.u[4] = f2bf(a1.x); A.u[5] = f2bf(a1.y); A.u[6] = f2bf(a1.z); A.u[7] = f2bf(a1.w);
#pragma unroll
    for (int ct = 0; ct < 4; ++ct) {
      union { uint4 q; bf16x8 v; } B;
      B.q = Wp[(ks * 4 + ct) * 64 + lane];
      acc[ct] = __builtin_amdgcn_mfma_f32_16x16x32_bf16(A.v, B.v, acc[ct], 0, 0, 0);
    }
  }

  const int cl = lane & 15, g = lane >> 4;
  float as_[4], ad_[4];
#pragma unroll
  for (int ct = 0; ct < 4; ++ct) { as_[ct] = a_src[ct * 16 + cl]; ad_[ct] = a_dst[ct * 16 + cl]; }

  float ms[4], md[4];
#pragma unroll
  for (int ct = 0; ct < 4; ++ct) { ms[ct] = -3.0e38f; md[ct] = -3.0e38f; }

#pragma unroll
  for (int j = 0; j < 4; ++j) {
    int r = r0 + g * 4 + j;
    bool rv = r < n_nodes;
    float ps[4], pd[4];
#pragma unroll
    for (int ct = 0; ct < 4; ++ct) {
      float v = acc[ct][j];
      if (rv) Whb[(size_t)r * OUT_C + ct * 16 + cl] = f2bf(v);
      ps[ct] = v * as_[ct];
      pd[ct] = v * ad_[ct];
    }
#pragma unroll
    for (int o = 1; o < 16; o <<= 1) {
#pragma unroll
      for (int ct = 0; ct < 4; ++ct) {
        ps[ct] += __shfl_xor(ps[ct], o);
        pd[ct] += __shfl_xor(pd[ct], o);
      }
    }
    if (rv && cl == 0) {
      ssrc4[r] = make_float4(ps[0], ps[1], ps[2], ps[3]);
      sdst4[r] = make_float4(pd[0], pd[1], pd[2], pd[3]);
    }
    if (rv) {
#pragma unroll
      for (int ct = 0; ct < 4; ++ct) {
        ms[ct] = fmaxf(ms[ct], ps[ct]);
        md[ct] = fmaxf(md[ct], pd[ct]);
      }
    }
  }
#pragma unroll
  for (int o = 16; o < 64; o <<= 1) {
#pragma unroll
    for (int ct = 0; ct < 4; ++ct) {
      ms[ct] = fmaxf(ms[ct], __shfl_xor(ms[ct], o));
      md[ct] = fmaxf(md[ct], __shfl_xor(md[ct], o));
    }
  }
  if (lane == 0) {
#pragma unroll
    for (int ct = 0; ct < 4; ++ct) { wmS[wid][ct] = ms[ct]; wmD[wid][ct] = md[ct]; }
  }
  __syncthreads();
  if (t < N_HEADS) {
    float vs = fmaxf(fmaxf(wmS[0][t], wmS[1][t]), fmaxf(wmS[2][t], wmS[3][t]));
    float vd = fmaxf(fmaxf(wmD[0][t], wmD[1][t]), fmaxf(wmD[2][t], wmD[3][t]));
    atomicMax(gmax_s + t, enc_f(vs));
    atomicMax(gmax_d + t, enc_f(vd));
  }
}

// ---- per-bucket LDS sort: inline gbase prefix, gather runs, sort by dst,
//      direct scatter to block-private global span fused with exp/gsum. ----
__global__ __launch_bounds__(256) void k_sortb(
    const int2* __restrict__ pairs, const int* __restrict__ boff,
    const int* __restrict__ btot, const float4* __restrict__ ssrc4,
    const float4* __restrict__ sdst4, const unsigned int* __restrict__ gmax_s,
    const unsigned int* __restrict__ gmax_d, float* __restrict__ gsum,
    int* __restrict__ sorted_src, int* __restrict__ offs,
    int npb, int nbkt, int n_edges, int n_nodes)
{
  const int b = blockIdx.x;
  const int t = threadIdx.x;
  const int lane = t & 63, wv = t >> 6;
  __shared__ int ts[256];
  __shared__ int hist[65];
  __shared__ int hcur[64];
  __shared__ int totsh, gbsh;
  __shared__ int gred[4];
  __shared__ float red[4][4];
  __shared__ int2 buf1[4096];   // 32 KB

  // inline gbase: gb = sum_{i<b} btot[i]
  {
    int partial = 0;
    for (int i = t; i < b; i += 256) partial += btot[i];
#pragma unroll
    for (int o = 32; o; o >>= 1) partial += __shfl_down(partial, o);
    if (lane == 0) gred[wv] = partial;
  }

  // per-run counts for this bucket + block scan -> staging bases
  int cnt = 0, bo = 0;
  if (t < npb) {
    const int* bp = boff + (size_t)t * (nbkt + 1) + b;
    bo = bp[0];
    cnt = bp[1] - bo;
  }
  ts[t] = cnt;
  __syncthreads();
  if (t == 0) gbsh = gred[0] + gred[1] + gred[2] + gred[3];
#pragma unroll
  for (int off = 1; off < 256; off <<= 1) {
    int v = (t >= off) ? ts[t - off] : 0;
    __syncthreads();
    ts[t] += v;
    __syncthreads();
  }
  int base = ts[t] - cnt;
  if (t == 255) totsh = ts[255];
  for (int i = t; i < 65; i += 256) hist[i] = 0;
  __syncthreads();
  const int total = min(totsh, 4096);   // statistically never clamps
  const int gb = gbsh;

  // gather this bucket's runs into LDS staging (thread t owns run t)
  if (cnt > 0 && base < 4096) {
    const int2* rp = pairs + (size_t)t * EPB + bo;
    int lim = min(cnt, 4096 - base);
    for (int j = 0; j < lim; ++j) buf1[base + j] = rp[j];
  }
  __syncthreads();

  // 64-bin histogram + prefix
  for (int i = t; i < total; i += 256) atomicAdd(&hist[buf1[i].y & 63], 1);
  __syncthreads();
  if (t == 0) {
    int run = 0;
#pragma unroll
    for (int i = 0; i < 64; ++i) { int c = hist[i]; hist[i] = run; run += c; }
    hist[64] = run;
  }
  __syncthreads();
  for (int i = t; i < 64; i += 256) hcur[i] = hist[i];
  __syncthreads();

  // scatter directly to global (block-private ~5KB span, L2-resident)
  // fused with weight exp + gsum accumulation
  float M0, M1, M2, M3;
  {
    float m0 = dec_f(gmax_s[0]) + dec_f(gmax_d[0]);
    float m1 = dec_f(gmax_s[1]) + dec_f(gmax_d[1]);
    float m2 = dec_f(gmax_s[2]) + dec_f(gmax_d[2]);
    float m3 = dec_f(gmax_s[3]) + dec_f(gmax_d[3]);
    M0 = m0 > 0.f ? m0 : ALPHA * m0;
    M1 = m1 > 0.f ? m1 : ALPHA * m1;
    M2 = m2 > 0.f ? m2 : ALPHA * m2;
    M3 = m3 > 0.f ? m3 : ALPHA * m3;
  }
  float ac0 = 0.f, ac1 = 0.f, ac2 = 0.f, ac3 = 0.f;
  for (int i = t; i < total; i += 256) {
    int2 p = buf1[i];
    int pos = atomicAdd(&hcur[p.y & 63], 1);
    sorted_src[gb + pos] = p.x;
    float4 a = ssrc4[p.x];
    float4 bb = sdst4[p.y];
    float e0 = a.x + bb.x; e0 = e0 > 0.f ? e0 : ALPHA * e0;
    float e1 = a.y + bb.y; e1 = e1 > 0.f ? e1 : ALPHA * e1;
    float e2 = a.z + bb.z; e2 = e2 > 0.f ? e2 : ALPHA * e2;
    float e3 = a.w + bb.w; e3 = e3 > 0.f ? e3 : ALPHA * e3;
    ac0 += __expf(e0 - M0); ac1 += __expf(e1 - M1);
    ac2 += __expf(e2 - M2); ac3 += __expf(e3 - M3);
  }

  // per-dst offsets straight from bin prefix
  if (t <= 64) {
    int d = b * TILE + t;
    if (d <= n_nodes) offs[d] = gb + hist[t];
  }

  // block reduce gsum partials -> 4 atomics
#pragma unroll
  for (int o = 32; o; o >>= 1) {
    ac0 += __shfl_down(ac0, o); ac1 += __shfl_down(ac1, o);
    ac2 += __shfl_down(ac2, o); ac3 += __shfl_down(ac3, o);
  }
  if (lane == 0) { red[wv][0] = ac0; red[wv][1] = ac1; red[wv][2] = ac2; red[wv][3] = ac3; }
  __syncthreads();
  if (t < 4) {
    float v = red[0][t] + red[1][t] + red[2][t] + red[3][t];
    atomicAdd(gsum + t, v);
  }
}

// ---- aggregate: wave per dst, quarter-wave per edge, 16 edges/iter (4-deep
//      ILP: four independent gather chains, named scalars only) ----
__global__ __launch_bounds__(256) void k_agg(
    const int* __restrict__ offs, const int* __restrict__ sorted_src,
    const float* __restrict__ ssrc, const float4* __restrict__ sdst4,
    const ushort* __restrict__ Whb, const unsigned int* __restrict__ gmax_s,
    const unsigned int* __restrict__ gmax_d, const float* __restrict__ gsum,
    float* __restrict__ out, int n_nodes)
{
  int d = blockIdx.x * 4 + (threadIdx.x >> 6);
  if (d >= n_nodes) return;
  const int lane = threadIdx.x & 63;
  const int g = lane >> 4;            // quarter index
  const int c4 = lane & 15;           // channel group
  const int head = c4 >> 2;
  float m = dec_f(gmax_s[head]) + dec_f(gmax_d[head]);
  float M = m > 0.f ? m : ALPHA * m;
  float inv = 1.f / gsum[head];
  float4 sd4 = sdst4[d];
  float sdh = head == 0 ? sd4.x : head == 1 ? sd4.y : head == 2 ? sd4.z : sd4.w;

  int beg = offs[d], end = offs[d + 1];
  float a0 = 0.f, a1 = 0.f, a2 = 0.f, a3 = 0.f;
  for (int j = beg; j < end; j += 16) {
    int je0 = j + g, je1 = j + 4 + g, je2 = j + 8 + g, je3 = j + 12 + g;
    bool v0 = je0 < end, v1 = je1 < end, v2 = je2 < end, v3 = je3 < end;
    int s0 = sorted_src[v0 ? je0 : beg];
    int s1 = sorted_src[v1 ? je1 : beg];
    int s2 = sorted_src[v2 ? je2 : beg];
    int s3 = sorted_src[v3 ? je3 : beg];
    float sc0 = ssrc[s0 * N_HEADS + head] + sdh;
    float sc1 = ssrc[s1 * N_HEADS + head] + sdh;
    float sc2 = ssrc[s2 * N_HEADS + head] + sdh;
    float sc3 = ssrc[s3 * N_HEADS + head] + sdh;
    sc0 = sc0 > 0.f ? sc0 : ALPHA * sc0;
    sc1 = sc1 > 0.f ? sc1 : ALPHA * sc1;
    sc2 = sc2 > 0.f ? sc2 : ALPHA * sc2;
    sc3 = sc3 > 0.f ? sc3 : ALPHA * sc3;
    float w0 = __expf(sc0 - M);
    float w1 = __expf(sc1 - M);
    float w2 = __expf(sc2 - M);
    float w3 = __expf(sc3 - M);
    w0 = v0 ? w0 : 0.f;
    w1 = v1 ? w1 : 0.f;
    w2 = v2 ? w2 : 0.f;
    w3 = v3 ? w3 : 0.f;
    ushort4 va = *(const ushort4*)(Whb + (size_t)s0 * OUT_C + c4 * 4);
    ushort4 vb = *(const ushort4*)(Whb + (size_t)s1 * OUT_C + c4 * 4);
    ushort4 vc = *(const ushort4*)(Whb + (size_t)s2 * OUT_C + c4 * 4);
    ushort4 vd = *(const ushort4*)(Whb + (size_t)s3 * OUT_C + c4 * 4);
    a0 += w0 * bf2f(va.x) + w1 * bf2f(vb.x) + w2 * bf2f(vc.x) + w3 * bf2f(vd.x);
    a1 += w0 * bf2f(va.y) + w1 * bf2f(vb.y) + w2 * bf2f(vc.y) + w3 * bf2f(vd.y);
    a2 += w0 * bf2f(va.z) + w1 * bf2f(vb.z) + w2 * bf2f(vc.z) + w3 * bf2f(vd.z);
    a3 += w0 * bf2f(va.w) + w1 * bf2f(vb.w) + w2 * bf2f(vc.w) + w3 * bf2f(vd.w);
  }
  // sum across the 4 quarters (lanes differing in bits 4,5)
  a0 += __shfl_xor(a0, 16); a1 += __shfl_xor(a1, 16);
  a2 += __shfl_xor(a2, 16); a3 += __shfl_xor(a3, 16);
  a0 += __shfl_xor(a0, 32); a1 += __shfl_xor(a1, 32);
  a2 += __shfl_xor(a2, 32); a3 += __shfl_xor(a3, 32);
  if (g == 0) {
    float4 o;
    o.x = fmaxf(a0 * inv, 0.f);
    o.y = fmaxf(a1 * inv, 0.f);
    o.z = fmaxf(a2 * inv, 0.f);
    o.w = fmaxf(a3 * inv, 0.f);
    ((float4*)(out + (size_t)d * OUT_C))[c4] = o;
  }
}

extern "C" void kernel_launch(void* const* d_in, const int* in_sizes, int n_in,
                              void* d_out, int out_size, void* d_ws, size_t ws_size,
                              hipStream_t stream) {
  const int*   ei    = (const int*)d_in[0];
  const float* h     = (const float*)d_in[1];
  const float* W     = (const float*)d_in[2];
  const float* a_src = (const float*)d_in[3];
  const float* a_dst = (const float*)d_in[4];
  float* out = (float*)d_out;

  const int n_edges = in_sizes[0] / 2;
  const int n_nodes = in_sizes[1] / IN_F;
  const int npb     = (n_edges + EPB - 1) / EPB;      // must be <= 256 (245 here)
  const int nbkt    = (n_nodes + TILE - 1) / TILE;    // must be <= 1024 (782 here)
  const int nmm     = (n_nodes + 63) / 64;

  char* ws = (char*)d_ws;
  size_t off = 0;
  auto alloc = [&](size_t bytes) { void* p = ws + off; off = (off + bytes + 15) & ~(size_t)15; return p; };
  ushort* Whb         = (ushort*)alloc((size_t)n_nodes * OUT_C * 2);
  float* ssrc         = (float*)alloc((size_t)n_nodes * N_HEADS * 4);
  float* sdst         = (float*)alloc((size_t)n_nodes * N_HEADS * 4);
  unsigned int* gmax_s= (unsigned int*)alloc(N_HEADS * 4);
  unsigned int* gmax_d= (unsigned int*)alloc(N_HEADS * 4);
  float* gsum         = (float*)alloc(N_HEADS * 4);
  int* btot           = (int*)alloc((size_t)nbkt * 4);
  int* offs           = (int*)alloc(((size_t)n_nodes + 1) * 4);
  int* sorted_src     = (int*)alloc((size_t)n_edges * 4);
  int2* pairs         = (int2*)alloc((size_t)npb * EPB * 8);
  int* boff           = (int*)alloc((size_t)npb * (nbkt + 1) * 4);
  uint4* Wp           = (uint4*)alloc(16 * 64 * 16);   // 16 KB packed W

  k_initpack<<<1, 256, 0, stream>>>(W, Wp, gmax_s, gmax_d, gsum, btot, nbkt);
  k_mmpart<<<npb + nmm, 256, 0, stream>>>(h, Wp, a_src, a_dst, Whb,
      (float4*)ssrc, (float4*)sdst, gmax_s, gmax_d,
      ei, pairs, boff, btot, n_nodes, n_edges, nbkt, npb);
  k_sortb<<<nbkt, 256, 0, stream>>>(pairs, boff, btot, (const float4*)ssrc,
      (const float4*)sdst, gmax_s, gmax_d, gsum, sorted_src, offs,
      npb, nbkt, n_edges, n_nodes);
  k_agg<<<(n_nodes + 3) / 4, 256, 0, stream>>>(offs, sorted_src, ssrc,
      (const float4*)sdst, Whb, gmax_s, gmax_d, gsum, out, n_nodes);
}